// Round 17
// baseline (185.141 us; speedup 1.0000x reference)
//
#include <hip/hip_runtime.h>
#include <hip/hip_bf16.h>

#define TWO_B 8192
#define HALF_B 4096
#define DIM 128
#define RPB 16                 // 16 rows/block -> grid 512 -> 2 blocks/CU
#define THREADS 1024
#define NWAVES (THREADS / 64)  // 16
#define KTOP 4095
// z scaled by sqrt((1/T)*log2(e)) -> MFMA output w = sim/T*log2(e); exp(sim/T)=exp2(w)
#define NRM_SCALE2 4.5398159f
#define LN2 0.69314718f
#define WLO (-0.28853900f)
#define WHI (0.28853900f)
#define NBINS 256
#define BIN_SCALE ((float)NBINS / (WHI - WLO))
#define INV_BIN_SCALE ((WHI - WLO) / (float)NBINS)
#define BIN_BIAS (-(WLO)*BIN_SCALE)

#define EXP2F(x) __builtin_amdgcn_exp2f(x)

typedef __bf16 bf16x8 __attribute__((ext_vector_type(8)));
typedef float f32x4 __attribute__((ext_vector_type(4)));

// ---- kernel 1: L2-normalize rows of z1,z2, scale by sqrt(log2e/T) -> bf16 z [8192][128] ----
__global__ __launch_bounds__(256) void nrm_kernel(const float* __restrict__ z1,
                                                  const float* __restrict__ z2,
                                                  ushort* __restrict__ zb) {
    const int lane = threadIdx.x & 63;
    const int row = blockIdx.x * 4 + (threadIdx.x >> 6);
    const float* src = (row < HALF_B) ? (z1 + (size_t)row * DIM)
                                      : (z2 + (size_t)(row - HALF_B) * DIM);
    float2 v = *reinterpret_cast<const float2*>(src + lane * 2);
    float ss = v.x * v.x + v.y * v.y;
#pragma unroll
    for (int off = 32; off; off >>= 1) ss += __shfl_xor(ss, off);
    const float inv = NRM_SCALE2 / fmaxf(sqrtf(ss), 1e-12f);
    __hip_bfloat16 a = __float2bfloat16(v.x * inv);
    __hip_bfloat16 b = __float2bfloat16(v.y * inv);
    ushort2 st;
    st.x = *reinterpret_cast<ushort*>(&a);
    st.y = *reinterpret_cast<ushort*>(&b);
    *reinterpret_cast<ushort2*>(zb + (size_t)row * DIM + lane * 2) = st;
}

// ---- kernel 2: 16 rows/block, grid 512 (2 blocks/CU, 32 free-running waves);
//      direct L2 loads (no staging, NO barriers in hot loop); windowed
//      count-only histogram (R12 math, absmax-verified) ----
// NOTE: plain __launch_bounds__ — min-waves VGPR caps spill (R7/R8). Natural
// VGPR must stay <=64 for 2 blocks/CU (tripwire: VGPR_Count / Occupancy).
__global__ __launch_bounds__(THREADS) void ntxent_kernel(const ushort* __restrict__ zb,
                                                         float* __restrict__ out) {
    __shared__ unsigned cntS[RPB / 2][NBINS + 1];  // u16-packed row-pair bin counts
    __shared__ float chunkF[RPB][16];
    __shared__ unsigned chunkC[RPB][16];
    __shared__ float sumHiS[RPB];
    __shared__ unsigned cntHiS[RPB];
    __shared__ float posS[RPB];

    const int tid = threadIdx.x;
    const int lane = tid & 63;
    const int wave = tid >> 6;
    const int rowbase = blockIdx.x * RPB;

    for (int i = tid; i < (RPB / 2) * (NBINS + 1); i += THREADS) (&cntS[0][0])[i] = 0u;
    if (tid < RPB) { sumHiS[tid] = 0.f; cntHiS[tid] = 0u; posS[tid] = 0.f; }
    __syncthreads();

    const int frow = lane & 15;
    const int kbase = (lane >> 4) * 8;
    const int drow = (lane >> 4) * 4;
    const int spD = rowbase;           // 16-col chunk containing the diagonal
    const int spP = rowbase ^ HALF_B;  // 16-col chunk containing the positives

    bf16x8 af[4];
    {
        const ushort* ap = zb + (size_t)(rowbase + frow) * DIM + kbase;
#pragma unroll
        for (int ks = 0; ks < 4; ++ks) af[ks] = *reinterpret_cast<const bf16x8*>(ap + ks * 32);
    }

    const ushort* zlane = zb + (size_t)frow * DIM + kbase;

#define COL16(J) (((J) >> 1) * (NWAVES * 32) + wave * 32 + (((J) & 1) << 4))

#define LOADF(DST, J)                                                            \
    {                                                                            \
        const ushort* _p = zlane + (size_t)COL16(J) * DIM;                       \
        _Pragma("unroll") for (int ks = 0; ks < 4; ++ks)                         \
            DST[ks] = *reinterpret_cast<const bf16x8*>(_p + ks * 32);            \
    }

#define MFMA4(BUF, ACC)                                                          \
    _Pragma("unroll") for (int ks = 0; ks < 4; ++ks) {                           \
        ACC = __builtin_amdgcn_mfma_f32_16x16x32_bf16(af[ks], BUF[ks], ACC, 0, 0, 0); \
    }

    unsigned cntHi = 0u;  // packed 4x8-bit high-count
    float sHi[4] = {0.f, 0.f, 0.f, 0.f};

#define EPI(ACC, COL, CHK)                                                       \
    _Pragma("unroll") for (int rg = 0; rg < 4; ++rg) {                           \
        const int grow = rowbase + drow + rg;                                    \
        const float v = ACC[rg];                                                 \
        bool use = true;                                                         \
        if (CHK) {                                                               \
            if ((COL) == grow) use = false;                                      \
            if ((COL) == (grow ^ HALF_B)) posS[drow + rg] = v;                   \
        }                                                                        \
        if (use) {                                                               \
            const float t = fmaf(v, BIN_SCALE, BIN_BIAS);                        \
            if (t >= (float)NBINS) {                                             \
                sHi[rg] += EXP2F(v);                                             \
                cntHi += (1u << (8 * rg));                                       \
            } else if (t >= 0.f) {                                               \
                const int bin = (int)t;                                          \
                atomicAdd(&cntS[(drow + rg) >> 1][bin], 1u << (16 * (rg & 1)));  \
            }                                                                    \
        }                                                                        \
    }

#define BODY(BUF, J)                                                             \
    {                                                                            \
        f32x4 acc = {0.f, 0.f, 0.f, 0.f};                                        \
        MFMA4(BUF, acc)                                                          \
        const int c16 = COL16(J);                                                \
        const int col = c16 + frow;                                              \
        if (c16 == spD || c16 == spP) {                                          \
            EPI(acc, col, true)                                                  \
        } else {                                                                 \
            EPI(acc, col, false)                                                 \
        }                                                                        \
    }

    // barrier-free main loop: 2-buffer rotation; exposed latency is hidden by
    // 32 unsynchronized waves/CU (2 blocks), not by intra-wave pipelining.
    bf16x8 bufA[4], bufB[4];
    LOADF(bufA, 0)
    for (int j = 0; j < 32; j += 2) {
        LOADF(bufB, j + 1)
        BODY(bufA, j)
        if (j + 2 < 32) LOADF(bufA, j + 2)
        BODY(bufB, j + 1)
    }

    // reduce high-count and high-sum across the 16 lanes sharing each row group
    {
        unsigned c[4];
        float f[4];
#pragma unroll
        for (int rg = 0; rg < 4; ++rg) {
            c[rg] = (cntHi >> (8 * rg)) & 0xffu;
            f[rg] = sHi[rg];
        }
#pragma unroll
        for (int rg = 0; rg < 4; ++rg) {
#pragma unroll
            for (int s = 1; s < 16; s <<= 1) {
                c[rg] += __shfl_xor(c[rg], s);
                f[rg] += __shfl_xor(f[rg], s);
            }
        }
        if ((lane & 15) == 0) {
#pragma unroll
            for (int rg = 0; rg < 4; ++rg) {
                atomicAdd(&cntHiS[drow + rg], c[rg]);
                atomicAdd(&sumHiS[drow + rg], f[rg]);
            }
        }
    }
    __syncthreads();

    // ---- per-row chunk sums (16 chunks of 16 bins, top-down); exp reconstructed
    //      from counts at bin midpoints ----
    if (tid < RPB * 16) {
        const int row = tid >> 4, c = tid & 15;
        const int btop = NBINS - 1 - c * 16;
        unsigned s = 0;
        float fs = 0.f;
#pragma unroll
        for (int t = 0; t < 16; ++t) {
            const unsigned w = cntS[row >> 1][btop - t];
            const unsigned h = (w >> (16 * (row & 1))) & 0xffffu;
            s += h;
            fs += (float)h * EXP2F(WLO + ((float)(btop - t) + 0.5f) * INV_BIN_SCALE);
        }
        chunkC[row][c] = s;
        chunkF[row][c] = fs;
    }
    __syncthreads();

    // ---- per-row threshold + hard-negative sum + loss ----
    if (tid < RPB) {
        const int row = tid;
        unsigned cum = cntHiS[row];
        float fAbove = sumHiS[row];
        float radd = 0.f;
        if (cum < (unsigned)KTOP) {
            int c = 0;
            for (; c < 16; ++c) {
                const unsigned cs = chunkC[row][c];
                if (cum + cs >= (unsigned)KTOP) break;
                cum += cs;
                fAbove += chunkF[row][c];
            }
            if (c < 16) {
                const int btop = NBINS - 1 - c * 16;
                for (int t = 0; t < 16; ++t) {
                    const unsigned w = cntS[row >> 1][btop - t];
                    const unsigned h = (w >> (16 * (row & 1))) & 0xffffu;
                    const float em = EXP2F(WLO + ((float)(btop - t) + 0.5f) * INV_BIN_SCALE);
                    if (cum + h >= (unsigned)KTOP) {
                        radd = (float)(KTOP - cum) * em;
                        break;
                    }
                    cum += h;
                    fAbove += (float)h * em;
                }
            }
        }
        const float hns = fAbove + radd;
        const float wpos = posS[row];
        float loss = logf(EXP2F(wpos) + hns) - wpos * LN2;
#pragma unroll
        for (int s = 1; s < 16; s <<= 1) loss += __shfl_xor(loss, s);
        if (tid == 0) atomicAdd(out, loss * (1.0f / (float)TWO_B));
    }
}

extern "C" void kernel_launch(void* const* d_in, const int* in_sizes, int n_in,
                              void* d_out, int out_size, void* d_ws, size_t ws_size,
                              hipStream_t stream) {
    const float* z1 = (const float*)d_in[0];
    const float* z2 = (const float*)d_in[1];
    float* out = (float*)d_out;
    ushort* zb = (ushort*)d_ws;  // 8192*128*2 = 2 MB

    hipMemsetAsync(d_out, 0, sizeof(float), stream);
    nrm_kernel<<<TWO_B / 4, 256, 0, stream>>>(z1, z2, zb);
    ntxent_kernel<<<TWO_B / RPB, THREADS, 0, stream>>>(zb, out);
}

// Round 18
// 148.111 us; speedup vs baseline: 1.2500x; 1.2500x over previous
//
#include <hip/hip_runtime.h>
#include <hip/hip_bf16.h>

#define TWO_B 8192
#define HALF_B 4096
#define DIM 128
#define RPB 32                    // rows per block (rowgroup)
#define THREADS 1024
#define NWAVES 16
#define SC 128                    // staged columns per iteration (32KB)
#define CPB 4096                  // columns per block (half split)
#define NT (CPB / SC)             // 32 iterations
#define KTOP 4095
// z scaled by sqrt((1/T)*log2(e)) -> MFMA output w = sim/T*log2(e); exp(sim/T)=exp2(w)
#define NRM_SCALE2 4.5398159f
#define LN2 0.69314718f
#define WLO (-0.28853900f)
#define WHI (0.28853900f)
#define NBINS 128
#define BIN_SCALE ((float)NBINS / (WHI - WLO))
#define INV_BIN_SCALE ((WHI - WLO) / (float)NBINS)
#define BIN_BIAS (-(WLO)*BIN_SCALE)

#define EXP2F(x) __builtin_amdgcn_exp2f(x)

typedef __bf16 bf16x8 __attribute__((ext_vector_type(8)));
typedef float f32x4 __attribute__((ext_vector_type(4)));

// ---- kernel 1: L2-normalize rows of z1,z2, scale by sqrt(log2e/T) -> bf16 z [8192][128] ----
__global__ __launch_bounds__(256) void nrm_kernel(const float* __restrict__ z1,
                                                  const float* __restrict__ z2,
                                                  ushort* __restrict__ zb) {
    const int lane = threadIdx.x & 63;
    const int row = blockIdx.x * 4 + (threadIdx.x >> 6);
    const float* src = (row < HALF_B) ? (z1 + (size_t)row * DIM)
                                      : (z2 + (size_t)(row - HALF_B) * DIM);
    float2 v = *reinterpret_cast<const float2*>(src + lane * 2);
    float ss = v.x * v.x + v.y * v.y;
#pragma unroll
    for (int off = 32; off; off >>= 1) ss += __shfl_xor(ss, off);
    const float inv = NRM_SCALE2 / fmaxf(sqrtf(ss), 1e-12f);
    __hip_bfloat16 a = __float2bfloat16(v.x * inv);
    __hip_bfloat16 b = __float2bfloat16(v.y * inv);
    ushort2 st;
    st.x = *reinterpret_cast<ushort*>(&a);
    st.y = *reinterpret_cast<ushort*>(&b);
    *reinterpret_cast<ushort2*>(zb + (size_t)row * DIM + lane * 2) = st;
}

// ---- kernel 2: COLUMN-SPLIT main pass. Block = 32 rows x 4096 cols (half).
// grid 512 -> 2 blocks/CU (R13-proven drain overlap) at R12's total staged
// traffic (512MB). Double-buffered 32KB stage, 1 barrier/iter. Partial
// histograms merged via device-scope global atomics; finalize kernel scans.
__global__ __launch_bounds__(THREADS) void ntxent_kernel(const ushort* __restrict__ zb,
                                                         unsigned* __restrict__ histG,
                                                         unsigned* __restrict__ cntHiG,
                                                         float* __restrict__ sumHiG,
                                                         float* __restrict__ posG) {
    __shared__ ushort stageS[2][SC * DIM];        // 2 x 32KB
    __shared__ unsigned histS[RPB / 2][NBINS + 1];  // u16-packed row-pair counts, 8.3KB

    const int tid = threadIdx.x;
    const int lane = tid & 63;
    const int wave = tid >> 6;
    const int rgp = blockIdx.x >> 1;   // rowgroup
    const int ch = blockIdx.x & 1;     // column half
    const int rowbase = rgp * RPB;
    const int colbase = ch * CPB;

    for (int i = tid; i < (RPB / 2) * (NBINS + 1); i += THREADS) (&histS[0][0])[i] = 0u;

    const int frow = lane & 15;
    const int kgrp = lane >> 4;   // 0..3
    const int rh = wave >> 3;     // row half (16 rows each)
    const int wc = wave & 7;      // col chunk (16 cols) within SC
    const int drow = kgrp * 4;

    bf16x8 af[4];
    {
        const ushort* ap = zb + (size_t)(rowbase + rh * 16 + frow) * DIM + kgrp * 8;
#pragma unroll
        for (int ks = 0; ks < 4; ++ks) af[ks] = *reinterpret_cast<const bf16x8*>(ap + ks * 32);
    }

    // wave-uniform special 16-col chunks (diag / positives of this wave's 16 rows)
    const int diagC = rowbase + rh * 16;
    const int posC = diagC ^ HALF_B;

    // staging: 32 chunks of 1KB; LDS dest linear, global source pre-swizzled
    // (inner ^= (col&7)<<4, m173) so swizzled ds_read below is conflict-free.
#define STAGE(BUF, T)                                                             \
    {                                                                             \
        const int cb0 = colbase + (T) * SC;                                       \
        _Pragma("unroll") for (int r = 0; r < 2; ++r) {                           \
            const int o = ((r * 16 + wave) * 64 + lane) * 16;                     \
            const int colL = o >> 8;                                              \
            const int innerp = o & 255;                                           \
            const int src_inner = innerp ^ ((colL & 7) << 4);                     \
            const ushort* gsrc = zb + (((size_t)(cb0 + colL)) << 7) + (src_inner >> 1); \
            __builtin_amdgcn_global_load_lds(                                     \
                (const __attribute__((address_space(1))) unsigned int*)gsrc,      \
                (__attribute__((address_space(3))) unsigned int*)(&stageS[BUF][(r * 16 + wave) * 512]), \
                16, 0, 0);                                                        \
        }                                                                         \
    }

#define LOADT(BUF, BF)                                                            \
    {                                                                             \
        const int colL = wc * 16 + frow;                                          \
        const int sw = (colL & 7) << 4;                                           \
        const char* bp = (const char*)&stageS[BUF][colL * DIM];                   \
        _Pragma("unroll") for (int ks = 0; ks < 4; ++ks) {                        \
            const int inner = kgrp * 16 + ks * 64;                                \
            BF[ks] = *reinterpret_cast<const bf16x8*>(bp + (inner ^ sw));         \
        }                                                                         \
    }

    unsigned cntHi = 0u;  // packed 4x8-bit (max NT=32 per slot)
    float sHi[4] = {0.f, 0.f, 0.f, 0.f};

#define EPI(ACC, COL, CHK)                                                       \
    _Pragma("unroll") for (int q = 0; q < 4; ++q) {                              \
        const int grow = rowbase + rh * 16 + drow + q;                           \
        const float v = ACC[q];                                                  \
        bool use = true;                                                         \
        if (CHK) {                                                               \
            if ((COL) == grow) use = false;                                      \
            if ((COL) == (grow ^ HALF_B)) posG[grow] = v;                        \
        }                                                                        \
        if (use) {                                                               \
            const float tt = fmaf(v, BIN_SCALE, BIN_BIAS);                       \
            if (tt >= (float)NBINS) {                                            \
                sHi[q] += EXP2F(v);                                              \
                cntHi += (1u << (8 * q));                                        \
            } else if (tt >= 0.f) {                                              \
                const int lr = rh * 16 + drow + q;                               \
                atomicAdd(&histS[lr >> 1][(int)tt], 1u << (16 * (lr & 1)));      \
            }                                                                    \
        }                                                                        \
    }

    STAGE(0, 0)
    __syncthreads();
    int cur = 0;
    for (int t = 0; t < NT; ++t) {
        if (t + 1 < NT) STAGE(cur ^ 1, t + 1)
        bf16x8 bf[4];
        LOADT(cur, bf)
        f32x4 acc = {0.f, 0.f, 0.f, 0.f};
#pragma unroll
        for (int ks = 0; ks < 4; ++ks)
            acc = __builtin_amdgcn_mfma_f32_16x16x32_bf16(af[ks], bf[ks], acc, 0, 0, 0);
        const int c16 = colbase + t * SC + wc * 16;
        const int col = c16 + frow;
        if (c16 == diagC || c16 == posC) {
            EPI(acc, col, true)
        } else {
            EPI(acc, col, false)
        }
        __syncthreads();
        cur ^= 1;
    }

    // reduce hi-count/hi-sum over the 16 col-lanes (frow), then global atomics
    {
        unsigned c[4];
        float f[4];
#pragma unroll
        for (int q = 0; q < 4; ++q) {
            c[q] = (cntHi >> (8 * q)) & 0xffu;
            f[q] = sHi[q];
        }
#pragma unroll
        for (int q = 0; q < 4; ++q) {
#pragma unroll
            for (int s = 1; s < 16; s <<= 1) {
                c[q] += __shfl_xor(c[q], s);
                f[q] += __shfl_xor(f[q], s);
            }
        }
        if (frow == 0) {
#pragma unroll
            for (int q = 0; q < 4; ++q) {
                const int grow = rowbase + rh * 16 + drow + q;
                atomicAdd(&cntHiG[grow], c[q]);
                atomicAdd(&sumHiG[grow], f[q]);
            }
        }
    }
    __syncthreads();

    // flush partial histogram to global (device-scope atomics; u16 halves safe:
    // two partials each <=4095 sum < 65536)
    for (int i = tid; i < (RPB / 2) * NBINS; i += THREADS) {
        const int rp = i >> 7, bin = i & (NBINS - 1);
        const unsigned w = histS[rp][bin];
        if (w) atomicAdd(&histG[(size_t)(rgp * 16 + rp) * NBINS + bin], w);
    }
}

// ---- kernel 3: per-row threshold scan + loss ----
__global__ __launch_bounds__(256) void fin_kernel(const unsigned* __restrict__ histG,
                                                  const unsigned* __restrict__ cntHiG,
                                                  const float* __restrict__ sumHiG,
                                                  const float* __restrict__ posG,
                                                  float* __restrict__ out) {
    __shared__ float red[4];
    const int tid = threadIdx.x;
    const int row = blockIdx.x * 256 + tid;

    unsigned cum = cntHiG[row];
    float fAbove = sumHiG[row];
    float radd = 0.f;
    if (cum < (unsigned)KTOP) {
        const unsigned* hrow = histG + (size_t)(row >> 1) * NBINS;
        const int sh = 16 * (row & 1);
        for (int bin = NBINS - 1; bin >= 0; --bin) {
            const unsigned h = (hrow[bin] >> sh) & 0xffffu;
            const float em = EXP2F(WLO + ((float)bin + 0.5f) * INV_BIN_SCALE);
            if (cum + h >= (unsigned)KTOP) {
                radd = (float)(KTOP - cum) * em;
                break;
            }
            cum += h;
            fAbove += (float)h * em;
        }
    }
    const float hns = fAbove + radd;
    const float wpos = posG[row];
    float loss = logf(EXP2F(wpos) + hns) - wpos * LN2;
#pragma unroll
    for (int s = 1; s < 64; s <<= 1) loss += __shfl_xor(loss, s);
    if ((tid & 63) == 0) red[tid >> 6] = loss;
    __syncthreads();
    if (tid == 0) atomicAdd(out, (red[0] + red[1] + red[2] + red[3]) * (1.0f / (float)TWO_B));
}

extern "C" void kernel_launch(void* const* d_in, const int* in_sizes, int n_in,
                              void* d_out, int out_size, void* d_ws, size_t ws_size,
                              hipStream_t stream) {
    const float* z1 = (const float*)d_in[0];
    const float* z2 = (const float*)d_in[1];
    float* out = (float*)d_out;
    // ws layout: [0,2MB) zb bf16 | [2MB,4MB) histG u32 4096x128 |
    //            [4MB,+32KB) cntHiG | +32KB sumHiG | +64KB posG  (total ~4.2MB)
    char* ws = (char*)d_ws;
    ushort* zb = (ushort*)ws;
    unsigned* histG = (unsigned*)(ws + (2u << 20));
    unsigned* cntHiG = (unsigned*)(ws + (4u << 20));
    float* sumHiG = (float*)(ws + (4u << 20) + 32768);
    float* posG = (float*)(ws + (4u << 20) + 65536);

    hipMemsetAsync(d_out, 0, sizeof(float), stream);
    hipMemsetAsync(ws + (2u << 20), 0, (2u << 20) + 65536, stream);  // hist+cntHi+sumHi
    nrm_kernel<<<TWO_B / 4, 256, 0, stream>>>(z1, z2, zb);
    ntxent_kernel<<<512, THREADS, 0, stream>>>(zb, histG, cntHiG, sumHiG, posG);
    fin_kernel<<<TWO_B / 256, 256, 0, stream>>>(histG, cntHiG, sumHiG, posG, out);
}